// Round 4
// baseline (1138.090 us; speedup 1.0000x reference)
//
#include <hip/hip_runtime.h>

// PathCon FFN — round 5: revert to ET=64 geometry + lgkm-only barriers +
// issue-early P/Q gather.
// All barriers in ffn order LDS only -> replace __syncthreads() (which drains
// vmcnt(0)) with s_waitcnt lgkmcnt(0); s_barrier. Global loads (P/Q gather,
// ea staging, out stores) stay in flight across barriers.
// P/Q residual: ei loaded at tile top, P/Q issued immediately, consumed after
// GEMM1 (~1.5k cycles of cover). 5 barriers/tile (LN stats via per-mg
// redundant reduce + shfl broadcast).

constexpr int NN = 50000;
constexpr int NE = 400000;
constexpr int DI = 128;
constexpr int DN = 6;
constexpr int DR = 134;
constexpr float LN_EPS = 1e-5f;

using f4 = __attribute__((ext_vector_type(4))) float;
using s8 = __attribute__((ext_vector_type(8))) short;

__device__ __forceinline__ unsigned short f2bf(float f) {
    unsigned u = __float_as_uint(f);
    u += 0x7fff + ((u >> 16) & 1);   // RNE
    return (unsigned short)(u >> 16);
}

__device__ __forceinline__ float bf2f(unsigned short b) {
    return __uint_as_float((unsigned)b << 16);
}

// Workgroup barrier that orders LDS only: does NOT drain vmcnt, so global
// loads/stores issued before it stay in flight across the barrier.
__device__ __forceinline__ void bar_lds() {
    __builtin_amdgcn_sched_barrier(0);
    asm volatile("s_waitcnt lgkmcnt(0)" ::: "memory");
    __builtin_amdgcn_s_barrier();
    __builtin_amdgcn_sched_barrier(0);
}

// Sum across each aligned 16-lane group via DPP row rotations.
__device__ __forceinline__ float red16(float v) {
    int x;
    x = __builtin_amdgcn_update_dpp(0, __float_as_int(v), 0x121, 0xf, 0xf, true); // row_ror:1
    v += __int_as_float(x);
    x = __builtin_amdgcn_update_dpp(0, __float_as_int(v), 0x122, 0xf, 0xf, true); // row_ror:2
    v += __int_as_float(x);
    x = __builtin_amdgcn_update_dpp(0, __float_as_int(v), 0x124, 0xf, 0xf, true); // row_ror:4
    v += __int_as_float(x);
    x = __builtin_amdgcn_update_dpp(0, __float_as_int(v), 0x128, 0xf, 0xf, true); // row_ror:8
    v += __int_as_float(x);
    return v;
}

// ------------------------------------------------------------ CSR build ---
__global__ __launch_bounds__(256) void deg_kernel(
    const float* __restrict__ mask, const int* __restrict__ ei,
    int* __restrict__ deg)
{
    int e = blockIdx.x * 256 + threadIdx.x;
    if (e >= NE) return;
    if (mask[e] != 0.f) atomicAdd(&deg[ei[NE + e]], 1);
}

__global__ __launch_bounds__(1024) void scan_kernel(
    const int* __restrict__ deg, int* __restrict__ offs, int* __restrict__ cursor)
{
    __shared__ int part[1024];
    const int t = threadIdx.x;
    constexpr int CH = (NN + 1023) / 1024;   // 49
    const int base = t * CH;
    const int lim  = min(base + CH, NN);

    int s = 0;
    for (int i = base; i < lim; ++i) s += deg[i];
    part[t] = s;
    __syncthreads();
    for (int off = 1; off < 1024; off <<= 1) {
        int add = (t >= off) ? part[t - off] : 0;
        __syncthreads();
        part[t] += add;
        __syncthreads();
    }
    int run = (t == 0) ? 0 : part[t - 1];
    for (int i = base; i < lim; ++i) {
        offs[i]   = run;
        cursor[i] = run;
        run += deg[i];
    }
    if (t == 1023) offs[NN] = part[1023];
}

__global__ __launch_bounds__(256) void binfill_kernel(
    const float* __restrict__ mask, const int* __restrict__ ei,
    int* __restrict__ cursor, int* __restrict__ bucket)
{
    int e = blockIdx.x * 256 + threadIdx.x;
    if (e >= NE) return;
    if (mask[e] != 0.f) {
        int pos = atomicAdd(&cursor[ei[NE + e]], 1);
        bucket[pos] = e;
    }
}

// one wave per node. mask is binary (0/1), so masked sum = plain sum of
// bucketed edges and den = bucket size.
__global__ __launch_bounds__(256) void gather_kernel(
    const float* __restrict__ edge_attr, const float* __restrict__ x,
    const int* __restrict__ offs, const int* __restrict__ bucket,
    float* __restrict__ node_out)
{
    int n = blockIdx.x * 4 + (threadIdx.x >> 6);
    if (n >= NN) return;
    const int lane = threadIdx.x & 63;
    const int beg = offs[n], end = offs[n + 1];
    float2 acc = make_float2(0.f, 0.f);
    for (int j = beg; j < end; ++j) {
        int e = bucket[j];
        float2 v = *reinterpret_cast<const float2*>(edge_attr + (size_t)e * 128 + lane * 2);
        acc.x += v.x;
        acc.y += v.y;
    }
    float inv = 1.f / (float)(end - beg + 1);
    float2 o = make_float2(acc.x * inv, acc.y * inv);
    *reinterpret_cast<float2*>(node_out + (size_t)n * DR + lane * 2) = o;
    if (lane < DN) node_out[(size_t)n * DR + DI + lane] = x[n * DN + lane];
}

// ----------------------------------------------------- bf16 weight prep ---
__global__ __launch_bounds__(256) void prep_w_kernel(
    const float* __restrict__ W_edge, const float* __restrict__ W1,
    const float* __restrict__ W2,
    unsigned short* __restrict__ WcT, unsigned short* __restrict__ W1T,
    unsigned short* __restrict__ W2T)
{
    int idx = blockIdx.x * 256 + threadIdx.x;
    if (idx < 16384) {
        int n = idx >> 7, k = idx & 127;
        float v = W_edge[(268 + k) * 128 + n] + (k == n ? 1.f : 0.f);
        WcT[n * 128 + k] = f2bf(v);
    } else if (idx < 49152) {
        int j = idx - 16384;
        int n = j >> 7, k = j & 127;
        W1T[n * 128 + k] = f2bf(W1[k * 256 + n]);
    } else if (idx < 81920) {
        int j = idx - 49152;
        int n = j >> 8, k = j & 255;
        W2T[n * 256 + k] = f2bf(W2[k * 128 + n]);
    }
}

// ------------------------------------------------ P/Q node-level GEMMs ---
__global__ __launch_bounds__(256) void pq_kernel(
    const float* __restrict__ nr, const float* __restrict__ W_edge,
    const float* __restrict__ b_edge,
    float* __restrict__ P, float* __restrict__ Q)
{
    __shared__ float As[64 * 136];
    const int t = threadIdx.x;
    const int n0 = blockIdx.x * 64;

    for (int idx = t; idx < 64 * 136; idx += 256) {
        int n = idx / 136, k = idx - n * 136;
        float v = 0.f;
        if (n0 + n < NN && k < DR) v = nr[(size_t)(n0 + n) * DR + k];
        As[idx] = v;
    }
    __syncthreads();

    const int et = t >> 5, jt = t & 31;
    float4 accP[8], accQ[8];
    #pragma unroll
    for (int i = 0; i < 8; ++i) {
        accP[i] = make_float4(0.f, 0.f, 0.f, 0.f);
        accQ[i] = make_float4(0.f, 0.f, 0.f, 0.f);
    }
    for (int k0 = 0; k0 < 136; k0 += 4) {
        float4 wa[4], wb[4];
        #pragma unroll
        for (int d = 0; d < 4; ++d) {
            wa[d] = *reinterpret_cast<const float4*>(&W_edge[(size_t)(k0 + d) * 128 + 4 * jt]);
            wb[d] = *reinterpret_cast<const float4*>(&W_edge[(size_t)(134 + k0 + d) * 128 + 4 * jt]);
        }
        #pragma unroll
        for (int i = 0; i < 8; ++i) {
            float4 a4 = *reinterpret_cast<const float4*>(&As[(8 * et + i) * 136 + k0]);
            accP[i].x += a4.x * wa[0].x + a4.y * wa[1].x + a4.z * wa[2].x + a4.w * wa[3].x;
            accP[i].y += a4.x * wa[0].y + a4.y * wa[1].y + a4.z * wa[2].y + a4.w * wa[3].y;
            accP[i].z += a4.x * wa[0].z + a4.y * wa[1].z + a4.z * wa[2].z + a4.w * wa[3].z;
            accP[i].w += a4.x * wa[0].w + a4.y * wa[1].w + a4.z * wa[2].w + a4.w * wa[3].w;
            accQ[i].x += a4.x * wb[0].x + a4.y * wb[1].x + a4.z * wb[2].x + a4.w * wb[3].x;
            accQ[i].y += a4.x * wb[0].y + a4.y * wb[1].y + a4.z * wb[2].y + a4.w * wb[3].y;
            accQ[i].z += a4.x * wb[0].z + a4.y * wb[1].z + a4.z * wb[2].z + a4.w * wb[3].z;
            accQ[i].w += a4.x * wb[0].w + a4.y * wb[1].w + a4.z * wb[2].w + a4.w * wb[3].w;
        }
    }
    float4 bev = *reinterpret_cast<const float4*>(&b_edge[4 * jt]);
    #pragma unroll
    for (int i = 0; i < 8; ++i) {
        int n = n0 + 8 * et + i;
        if (n < NN) {
            float4 p = accP[i];
            p.x += bev.x; p.y += bev.y; p.z += bev.z; p.w += bev.w;
            *reinterpret_cast<float4*>(&P[(size_t)n * 128 + 4 * jt]) = p;
            *reinterpret_cast<float4*>(&Q[(size_t)n * 128 + 4 * jt]) = accQ[i];
        }
    }
}

// -------------------------------------------------------------- fused FFN ---
// 1024 thr = 16 waves = 2 m-groups (32 edges) x 8 col-waves; ET=64; grid 256
// (1 block/CU). Weights in VGPRs. XOR-swizzled LDS (chunk ^= row&7).
constexpr int ET = 64;
constexpr int NTILE = NE / ET;   // 6250
constexpr int FFN_GRID = 256;

__global__ __launch_bounds__(1024, 4) void ffn_kernel(
    const float* __restrict__ edge_attr,  // [NE, 128]
    const int* __restrict__ ei,           // [2, NE]
    const float* __restrict__ P,          // [NN, 128]
    const float* __restrict__ Q,          // [NN, 128]
    const unsigned short* __restrict__ WcT,   // [128][128] bf16 (Wc+I)^T
    const unsigned short* __restrict__ W1T,   // [256][128] bf16
    const unsigned short* __restrict__ W2T,   // [128][256] bf16
    const float* __restrict__ b1, const float* __restrict__ b2,
    const float* __restrict__ g1, const float* __restrict__ be1,
    const float* __restrict__ g2, const float* __restrict__ be2,
    float* __restrict__ out)              // [NE, 128]
{
    __shared__ short lds_a[ET * 128];         // ea tile, later h tile (16 KB)
    __shared__ short lds_u[ET * 256];         // u tile (32 KB)
    __shared__ float red_part[2][8][32][2];   // [mg][cw][row][s,ss] (4 KB)

    const int t    = threadIdx.x;
    const int w    = t >> 6;
    const int lane = t & 63;
    const int q    = lane >> 4;     // 0..3
    const int c    = lane & 15;     // 0..15
    const int mg   = w >> 3;        // 0..1
    const int cw   = w & 7;         // 0..7

    // ---- persistent weight fragments (loaded once per block) ----
    s8 wcf[4], w1f[2][4], w2f[8];
    #pragma unroll
    for (int k0 = 0; k0 < 4; ++k0)
        wcf[k0] = *reinterpret_cast<const s8*>(WcT + (cw * 16 + c) * 128 + k0 * 32 + q * 8);
    #pragma unroll
    for (int nt = 0; nt < 2; ++nt)
        #pragma unroll
        for (int k0 = 0; k0 < 4; ++k0)
            w1f[nt][k0] = *reinterpret_cast<const s8*>(W1T + (cw * 32 + nt * 16 + c) * 128 + k0 * 32 + q * 8);
    #pragma unroll
    for (int k0 = 0; k0 < 8; ++k0)
        w2f[k0] = *reinterpret_cast<const s8*>(W2T + (cw * 16 + c) * 256 + k0 * 32 + q * 8);

    const float g1c  = g1[cw * 16 + c],  be1c = be1[cw * 16 + c];
    const float b1v0 = b1[cw * 32 + c],  b1v1 = b1[cw * 32 + 16 + c];
    const float b2c  = b2[cw * 16 + c];
    const float g2c  = g2[cw * 16 + c],  be2c = be2[cw * 16 + c];

    const int srow = t >> 4;    // staging row 0..63
    const int sti  = t & 15;    // staging 16B-chunk index

    for (int tile = blockIdx.x; tile < NTILE; tile += gridDim.x) {
        const int e0 = tile * ET;
        const int eb = e0 + mg * 32;

        // ---- issue-early: ei loads, then P/Q gathers (fly across bar A) ----
        int er[2][4], ec[2][4];
        #pragma unroll
        for (int mt = 0; mt < 2; ++mt)
            #pragma unroll
            for (int reg = 0; reg < 4; ++reg) {
                int e = eb + mt * 16 + q * 4 + reg;
                er[mt][reg] = ei[e];
                ec[mt][reg] = ei[NE + e];
            }
        float pr[2][4], qr[2][4];
        #pragma unroll
        for (int mt = 0; mt < 2; ++mt)
            #pragma unroll
            for (int reg = 0; reg < 4; ++reg) {
                pr[mt][reg] = P[(size_t)er[mt][reg] * 128 + cw * 16 + c];
                qr[mt][reg] = Q[(size_t)ec[mt][reg] * 128 + cw * 16 + c];
            }

        // ---- stage ea tile -> bf16 LDS (swizzled) ----
        {
            const float4* src = reinterpret_cast<const float4*>(
                edge_attr + (size_t)(e0 + srow) * 128 + sti * 8);
            float4 v0 = src[0], v1 = src[1];
            s8 bb;
            bb[0] = (short)f2bf(v0.x); bb[1] = (short)f2bf(v0.y);
            bb[2] = (short)f2bf(v0.z); bb[3] = (short)f2bf(v0.w);
            bb[4] = (short)f2bf(v1.x); bb[5] = (short)f2bf(v1.y);
            bb[6] = (short)f2bf(v1.z); bb[7] = (short)f2bf(v1.w);
            *reinterpret_cast<s8*>(&lds_a[srow * 128 + (sti ^ (srow & 7)) * 8]) = bb;
        }
        bar_lds();                                         // (A) ea ready

        // ---- GEMM1: ea @ (Wc+I) ----
        f4 acc1[2];
        acc1[0] = {0.f, 0.f, 0.f, 0.f};
        acc1[1] = {0.f, 0.f, 0.f, 0.f};
        #pragma unroll
        for (int k0 = 0; k0 < 4; ++k0)
            #pragma unroll
            for (int mt = 0; mt < 2; ++mt) {
                s8 a = *reinterpret_cast<const s8*>(
                    &lds_a[(mg * 32 + mt * 16 + c) * 128 + ((k0 * 4 + q) ^ (c & 7)) * 8]);
                acc1[mt] = __builtin_amdgcn_mfma_f32_16x16x32_bf16(a, wcf[k0], acc1[mt], 0, 0, 0);
            }

        // ---- residual: consume prefetched P/Q ----
        #pragma unroll
        for (int mt = 0; mt < 2; ++mt)
            #pragma unroll
            for (int reg = 0; reg < 4; ++reg)
                acc1[mt][reg] += pr[mt][reg] + qr[mt][reg];

        // ---- LN1 partials -> red_part[mg][cw][r] ----
        #pragma unroll
        for (int mt = 0; mt < 2; ++mt)
            #pragma unroll
            for (int reg = 0; reg < 4; ++reg) {
                float v  = acc1[mt][reg];
                float sv = red16(v);
                float sq = red16(v * v);
                if (c == 0) {
                    int r = mt * 16 + q * 4 + reg;
                    float2 p2; p2.x = sv; p2.y = sq;
                    *reinterpret_cast<float2*>(&red_part[mg][cw][r][0]) = p2;
                }
            }
        bar_lds();                                         // (B) partials ready

        // ---- LN1 stats: each wave reduces its mg's 32 rows, shfl broadcast ----
        float mu_l = 0.f, rs_l = 0.f;
        if (lane < 32) {
            float s = 0.f, ss = 0.f;
            #pragma unroll
            for (int i = 0; i < 8; ++i) {
                float2 p2 = *reinterpret_cast<const float2*>(&red_part[mg][i][lane][0]);
                s += p2.x; ss += p2.y;
            }
            mu_l = s * (1.f / 128.f);
            float var = ss * (1.f / 128.f) - mu_l * mu_l;
            rs_l = rsqrtf(var + LN_EPS);
        }

        // ---- normalize -> h (bf16, swizzled) into lds_a ----
        #pragma unroll
        for (int mt = 0; mt < 2; ++mt)
            #pragma unroll
            for (int reg = 0; reg < 4; ++reg) {
                int r  = mt * 16 + q * 4 + reg;          // within-mg row
                int gr = mg * 32 + r;
                float mu = __shfl(mu_l, r, 64);
                float rs = __shfl(rs_l, r, 64);
                float h = (acc1[mt][reg] - mu) * rs * g1c + be1c;
                lds_a[gr * 128 + ((cw * 2 + (c >> 3)) ^ (r & 7)) * 8 + (c & 7)] = (short)f2bf(h);
            }
        bar_lds();                                         // (D) h ready

        // ---- GEMM2: u = relu(h @ W1 + b1) ----
        f4 acc2[2][2];
        acc2[0][0] = {0.f,0.f,0.f,0.f}; acc2[0][1] = {0.f,0.f,0.f,0.f};
        acc2[1][0] = {0.f,0.f,0.f,0.f}; acc2[1][1] = {0.f,0.f,0.f,0.f};
        #pragma unroll
        for (int k0 = 0; k0 < 4; ++k0)
            #pragma unroll
            for (int mt = 0; mt < 2; ++mt) {
                s8 a = *reinterpret_cast<const s8*>(
                    &lds_a[(mg * 32 + mt * 16 + c) * 128 + ((k0 * 4 + q) ^ (c & 7)) * 8]);
                acc2[mt][0] = __builtin_amdgcn_mfma_f32_16x16x32_bf16(a, w1f[0][k0], acc2[mt][0], 0, 0, 0);
                acc2[mt][1] = __builtin_amdgcn_mfma_f32_16x16x32_bf16(a, w1f[1][k0], acc2[mt][1], 0, 0, 0);
            }
        #pragma unroll
        for (int mt = 0; mt < 2; ++mt)
            #pragma unroll
            for (int reg = 0; reg < 4; ++reg) {
                int r  = mt * 16 + q * 4 + reg;
                int gr = mg * 32 + r;
                float u0 = fmaxf(acc2[mt][0][reg] + b1v0, 0.f);
                float u1 = fmaxf(acc2[mt][1][reg] + b1v1, 0.f);
                int ch0 = (cw * 4 + (c >> 3)) ^ (r & 7);
                int ch1 = (cw * 4 + 2 + (c >> 3)) ^ (r & 7);
                lds_u[gr * 256 + ch0 * 8 + (c & 7)] = (short)f2bf(u0);
                lds_u[gr * 256 + ch1 * 8 + (c & 7)] = (short)f2bf(u1);
            }
        bar_lds();                                         // (E) u ready

        // ---- GEMM3: y = h + u @ W2 + b2 (K=256) ----
        f4 acc3[2];
        #pragma unroll
        for (int mt = 0; mt < 2; ++mt)
            #pragma unroll
            for (int reg = 0; reg < 4; ++reg) {
                int r  = mt * 16 + q * 4 + reg;
                int gr = mg * 32 + r;
                acc3[mt][reg] = bf2f((unsigned short)
                    lds_a[gr * 128 + ((cw * 2 + (c >> 3)) ^ (r & 7)) * 8 + (c & 7)]) + b2c;
            }
        #pragma unroll
        for (int k0 = 0; k0 < 8; ++k0)
            #pragma unroll
            for (int mt = 0; mt < 2; ++mt) {
                s8 a = *reinterpret_cast<const s8*>(
                    &lds_u[(mg * 32 + mt * 16 + c) * 256 + ((k0 * 4 + q) ^ (c & 7)) * 8]);
                acc3[mt] = __builtin_amdgcn_mfma_f32_16x16x32_bf16(a, w2f[k0], acc3[mt], 0, 0, 0);
            }

        // ---- LN2 partials ----
        #pragma unroll
        for (int mt = 0; mt < 2; ++mt)
            #pragma unroll
            for (int reg = 0; reg < 4; ++reg) {
                float v  = acc3[mt][reg];
                float sv = red16(v);
                float sq = red16(v * v);
                if (c == 0) {
                    int r = mt * 16 + q * 4 + reg;
                    float2 p2; p2.x = sv; p2.y = sq;
                    *reinterpret_cast<float2*>(&red_part[mg][cw][r][0]) = p2;
                }
            }
        bar_lds();                                         // (F) partials ready

        float mu2_l = 0.f, rs2_l = 0.f;
        if (lane < 32) {
            float s = 0.f, ss = 0.f;
            #pragma unroll
            for (int i = 0; i < 8; ++i) {
                float2 p2 = *reinterpret_cast<const float2*>(&red_part[mg][i][lane][0]);
                s += p2.x; ss += p2.y;
            }
            mu2_l = s * (1.f / 128.f);
            float var = ss * (1.f / 128.f) - mu2_l * mu2_l;
            rs2_l = rsqrtf(var + LN_EPS);
        }

        // ---- epilogue store ----
        #pragma unroll
        for (int mt = 0; mt < 2; ++mt)
            #pragma unroll
            for (int reg = 0; reg < 4; ++reg) {
                int r  = mt * 16 + q * 4 + reg;
                int gr = mg * 32 + r;
                float mu = __shfl(mu2_l, r, 64);
                float rs = __shfl(rs2_l, r, 64);
                float o = (acc3[mt][reg] - mu) * rs * g2c + be2c;
                out[(size_t)(e0 + gr) * 128 + cw * 16 + c] = o;
            }
    }
}

// ------------------------------------------------------------------ launch ---
extern "C" void kernel_launch(void* const* d_in, const int* in_sizes, int n_in,
                              void* d_out, int out_size, void* d_ws, size_t ws_size,
                              hipStream_t stream) {
    const float* x         = (const float*)d_in[0];
    const int*   ei        = (const int*)  d_in[1];
    const float* edge_attr = (const float*)d_in[2];
    const float* mask      = (const float*)d_in[3];
    const float* W_edge    = (const float*)d_in[5];
    const float* b_edge    = (const float*)d_in[6];
    const float* W1        = (const float*)d_in[7];
    const float* b1        = (const float*)d_in[8];
    const float* W2        = (const float*)d_in[9];
    const float* b2        = (const float*)d_in[10];
    const float* g1        = (const float*)d_in[11];
    const float* be1       = (const float*)d_in[12];
    const float* g2        = (const float*)d_in[13];
    const float* be2       = (const float*)d_in[14];

    float* node_out  = (float*)d_out;                       // [NN, DR]
    float* out_edges = (float*)d_out + (size_t)NN * DR;     // [NE, 128]

    char* ws = (char*)d_ws;
    int*            deg    = (int*)(ws);                         // 256 KB region
    int*            offs   = (int*)(ws + (256 << 10));           // 256 KB (NN+1 ints)
    int*            cursor = (int*)(ws + (512 << 10));           // 256 KB
    unsigned short* WcT    = (unsigned short*)(ws + (768 << 10));          // 32 KB
    unsigned short* W1T    = (unsigned short*)(ws + (768 << 10) + 32768);  // 64 KB
    unsigned short* W2T    = (unsigned short*)(ws + (768 << 10) + 98304);  // 64 KB
    int*            bucket = (int*)(ws + (1 << 20));             // 1.6 MB, aliases P (dead until pq)
    float*          P      = (float*)(ws + (1 << 20));           // 25.6 MB
    float*          Q      = (float*)(ws + (1 << 20) + 26214400);// 25.6 MB

    hipMemsetAsync(deg, 0, (size_t)NN * sizeof(int), stream);

    deg_kernel<<<(NE + 255) / 256, 256, 0, stream>>>(mask, ei, deg);
    scan_kernel<<<1, 1024, 0, stream>>>(deg, offs, cursor);
    binfill_kernel<<<(NE + 255) / 256, 256, 0, stream>>>(mask, ei, cursor, bucket);
    gather_kernel<<<(NN + 3) / 4, 256, 0, stream>>>(edge_attr, x, offs, bucket, node_out);
    prep_w_kernel<<<320, 256, 0, stream>>>(W_edge, W1, W2, WcT, W1T, W2T);
    pq_kernel<<<(NN + 63) / 64, 256, 0, stream>>>(node_out, W_edge, b_edge, P, Q);
    ffn_kernel<<<FFN_GRID, 1024, 0, stream>>>(edge_attr, ei, P, Q, WcT, W1T, W2T,
                                              b1, b2, g1, be1, g2, be2, out_edges);
}

// Round 5
// 1078.754 us; speedup vs baseline: 1.0550x; 1.0550x over previous
//
#include <hip/hip_runtime.h>

// PathCon FFN — round 6: restore v2 lockstep ffn + one-tile-ahead pipelining.
// Post-mortem r3/r4: loosening lockstep (2 blocks/CU, lgkm-only barriers)
// destroyed L2 merge of sub-line P/Q gathers and out stores (FETCH 450->1110 MB).
// This version: v2 geometry (1024 thr, ET=64, grid 256, plain __syncthreads,
// PA=136/PU=264 pitches), weights in VGPRs, PLUS:
//  - P/Q residuals prefetched into registers one tile ahead (zero-stall consume)
//  - ea tile staged into double-buffered LDS one tile ahead
//  - ei loads vectorized int4, issued before GEMM1
//  - 5 barriers/tile (LN stats via per-mg redundant reduce + shfl broadcast)
// All prefetches issue at the same program point in every wave -> lockstep kept.

constexpr int NN = 50000;
constexpr int NE = 400000;
constexpr int DI = 128;
constexpr int DN = 6;
constexpr int DR = 134;
constexpr float LN_EPS = 1e-5f;

using f4 = __attribute__((ext_vector_type(4))) float;
using s8 = __attribute__((ext_vector_type(8))) short;

__device__ __forceinline__ unsigned short f2bf(float f) {
    unsigned u = __float_as_uint(f);
    u += 0x7fff + ((u >> 16) & 1);   // RNE
    return (unsigned short)(u >> 16);
}

__device__ __forceinline__ float bf2f(unsigned short b) {
    return __uint_as_float((unsigned)b << 16);
}

// Sum across each aligned 16-lane group via DPP row rotations.
__device__ __forceinline__ float red16(float v) {
    int x;
    x = __builtin_amdgcn_update_dpp(0, __float_as_int(v), 0x121, 0xf, 0xf, true); // row_ror:1
    v += __int_as_float(x);
    x = __builtin_amdgcn_update_dpp(0, __float_as_int(v), 0x122, 0xf, 0xf, true); // row_ror:2
    v += __int_as_float(x);
    x = __builtin_amdgcn_update_dpp(0, __float_as_int(v), 0x124, 0xf, 0xf, true); // row_ror:4
    v += __int_as_float(x);
    x = __builtin_amdgcn_update_dpp(0, __float_as_int(v), 0x128, 0xf, 0xf, true); // row_ror:8
    v += __int_as_float(x);
    return v;
}

// ------------------------------------------------------------ CSR build ---
__global__ __launch_bounds__(256) void deg_kernel(
    const float* __restrict__ mask, const int* __restrict__ ei,
    int* __restrict__ deg)
{
    int e = blockIdx.x * 256 + threadIdx.x;
    if (e >= NE) return;
    if (mask[e] != 0.f) atomicAdd(&deg[ei[NE + e]], 1);
}

__global__ __launch_bounds__(1024) void scan_kernel(
    const int* __restrict__ deg, int* __restrict__ offs, int* __restrict__ cursor)
{
    __shared__ int part[1024];
    const int t = threadIdx.x;
    constexpr int CH = (NN + 1023) / 1024;   // 49
    const int base = t * CH;
    const int lim  = min(base + CH, NN);

    int s = 0;
    for (int i = base; i < lim; ++i) s += deg[i];
    part[t] = s;
    __syncthreads();
    for (int off = 1; off < 1024; off <<= 1) {
        int add = (t >= off) ? part[t - off] : 0;
        __syncthreads();
        part[t] += add;
        __syncthreads();
    }
    int run = (t == 0) ? 0 : part[t - 1];
    for (int i = base; i < lim; ++i) {
        offs[i]   = run;
        cursor[i] = run;
        run += deg[i];
    }
    if (t == 1023) offs[NN] = part[1023];
}

__global__ __launch_bounds__(256) void binfill_kernel(
    const float* __restrict__ mask, const int* __restrict__ ei,
    int* __restrict__ cursor, int* __restrict__ bucket)
{
    int e = blockIdx.x * 256 + threadIdx.x;
    if (e >= NE) return;
    if (mask[e] != 0.f) {
        int pos = atomicAdd(&cursor[ei[NE + e]], 1);
        bucket[pos] = e;
    }
}

// one wave per node. mask is binary (0/1), so masked sum = plain sum of
// bucketed edges and den = bucket size.
__global__ __launch_bounds__(256) void gather_kernel(
    const float* __restrict__ edge_attr, const float* __restrict__ x,
    const int* __restrict__ offs, const int* __restrict__ bucket,
    float* __restrict__ node_out)
{
    int n = blockIdx.x * 4 + (threadIdx.x >> 6);
    if (n >= NN) return;
    const int lane = threadIdx.x & 63;
    const int beg = offs[n], end = offs[n + 1];
    float2 acc = make_float2(0.f, 0.f);
    for (int j = beg; j < end; ++j) {
        int e = bucket[j];
        float2 v = *reinterpret_cast<const float2*>(edge_attr + (size_t)e * 128 + lane * 2);
        acc.x += v.x;
        acc.y += v.y;
    }
    float inv = 1.f / (float)(end - beg + 1);
    float2 o = make_float2(acc.x * inv, acc.y * inv);
    *reinterpret_cast<float2*>(node_out + (size_t)n * DR + lane * 2) = o;
    if (lane < DN) node_out[(size_t)n * DR + DI + lane] = x[n * DN + lane];
}

// ----------------------------------------------------- bf16 weight prep ---
__global__ __launch_bounds__(256) void prep_w_kernel(
    const float* __restrict__ W_edge, const float* __restrict__ W1,
    const float* __restrict__ W2,
    unsigned short* __restrict__ WcT, unsigned short* __restrict__ W1T,
    unsigned short* __restrict__ W2T)
{
    int idx = blockIdx.x * 256 + threadIdx.x;
    if (idx < 16384) {
        int n = idx >> 7, k = idx & 127;
        float v = W_edge[(268 + k) * 128 + n] + (k == n ? 1.f : 0.f);
        WcT[n * 128 + k] = f2bf(v);
    } else if (idx < 49152) {
        int j = idx - 16384;
        int n = j >> 7, k = j & 127;
        W1T[n * 128 + k] = f2bf(W1[k * 256 + n]);
    } else if (idx < 81920) {
        int j = idx - 49152;
        int n = j >> 8, k = j & 255;
        W2T[n * 256 + k] = f2bf(W2[k * 128 + n]);
    }
}

// ------------------------------------------------ P/Q node-level GEMMs ---
__global__ __launch_bounds__(256) void pq_kernel(
    const float* __restrict__ nr, const float* __restrict__ W_edge,
    const float* __restrict__ b_edge,
    float* __restrict__ P, float* __restrict__ Q)
{
    __shared__ float As[64 * 136];
    const int t = threadIdx.x;
    const int n0 = blockIdx.x * 64;

    for (int idx = t; idx < 64 * 136; idx += 256) {
        int n = idx / 136, k = idx - n * 136;
        float v = 0.f;
        if (n0 + n < NN && k < DR) v = nr[(size_t)(n0 + n) * DR + k];
        As[idx] = v;
    }
    __syncthreads();

    const int et = t >> 5, jt = t & 31;
    float4 accP[8], accQ[8];
    #pragma unroll
    for (int i = 0; i < 8; ++i) {
        accP[i] = make_float4(0.f, 0.f, 0.f, 0.f);
        accQ[i] = make_float4(0.f, 0.f, 0.f, 0.f);
    }
    for (int k0 = 0; k0 < 136; k0 += 4) {
        float4 wa[4], wb[4];
        #pragma unroll
        for (int d = 0; d < 4; ++d) {
            wa[d] = *reinterpret_cast<const float4*>(&W_edge[(size_t)(k0 + d) * 128 + 4 * jt]);
            wb[d] = *reinterpret_cast<const float4*>(&W_edge[(size_t)(134 + k0 + d) * 128 + 4 * jt]);
        }
        #pragma unroll
        for (int i = 0; i < 8; ++i) {
            float4 a4 = *reinterpret_cast<const float4*>(&As[(8 * et + i) * 136 + k0]);
            accP[i].x += a4.x * wa[0].x + a4.y * wa[1].x + a4.z * wa[2].x + a4.w * wa[3].x;
            accP[i].y += a4.x * wa[0].y + a4.y * wa[1].y + a4.z * wa[2].y + a4.w * wa[3].y;
            accP[i].z += a4.x * wa[0].z + a4.y * wa[1].z + a4.z * wa[2].z + a4.w * wa[3].z;
            accP[i].w += a4.x * wa[0].w + a4.y * wa[1].w + a4.z * wa[2].w + a4.w * wa[3].w;
            accQ[i].x += a4.x * wb[0].x + a4.y * wb[1].x + a4.z * wb[2].x + a4.w * wb[3].x;
            accQ[i].y += a4.x * wb[0].y + a4.y * wb[1].y + a4.z * wb[2].y + a4.w * wb[3].y;
            accQ[i].z += a4.x * wb[0].z + a4.y * wb[1].z + a4.z * wb[2].z + a4.w * wb[3].z;
            accQ[i].w += a4.x * wb[0].w + a4.y * wb[1].w + a4.z * wb[2].w + a4.w * wb[3].w;
        }
    }
    float4 bev = *reinterpret_cast<const float4*>(&b_edge[4 * jt]);
    #pragma unroll
    for (int i = 0; i < 8; ++i) {
        int n = n0 + 8 * et + i;
        if (n < NN) {
            float4 p = accP[i];
            p.x += bev.x; p.y += bev.y; p.z += bev.z; p.w += bev.w;
            *reinterpret_cast<float4*>(&P[(size_t)n * 128 + 4 * jt]) = p;
            *reinterpret_cast<float4*>(&Q[(size_t)n * 128 + 4 * jt]) = accQ[i];
        }
    }
}

// -------------------------------------------------------------- fused FFN ---
// 1024 thr = 16 waves = 2 m-groups (32 edges) x 8 col-waves; ET=64; grid 256.
constexpr int PA = 136;          // pitch (shorts) of ea/h tile rows (272 B = 17*16)
constexpr int PU = 264;          // pitch (shorts) of u tile rows   (528 B = 33*16)
constexpr int ET = 64;
constexpr int NTILE = NE / ET;   // 6250
constexpr int FFN_GRID = 256;

__global__ __launch_bounds__(1024, 4) void ffn_kernel(
    const float* __restrict__ edge_attr,  // [NE, 128]
    const int* __restrict__ ei,           // [2, NE]
    const float* __restrict__ P,          // [NN, 128]
    const float* __restrict__ Q,          // [NN, 128]
    const unsigned short* __restrict__ WcT,   // [128][128] bf16 (Wc+I)^T
    const unsigned short* __restrict__ W1T,   // [256][128] bf16
    const unsigned short* __restrict__ W2T,   // [128][256] bf16
    const float* __restrict__ b1, const float* __restrict__ b2,
    const float* __restrict__ g1, const float* __restrict__ be1,
    const float* __restrict__ g2, const float* __restrict__ be2,
    float* __restrict__ out)              // [NE, 128]
{
    __shared__ short lds_a[2 * ET * PA];      // double-buffered ea/h (34.8 KB)
    __shared__ short lds_u[ET * PU];          // u tile (33.8 KB)
    __shared__ float red_part[2][8][32][2];   // [mg][cw][row][s,ss] (4 KB)

    const int t    = threadIdx.x;
    const int w    = t >> 6;
    const int lane = t & 63;
    const int q    = lane >> 4;     // 0..3
    const int c    = lane & 15;     // 0..15
    const int mg   = w >> 3;        // 0..1
    const int cw   = w & 7;         // 0..7

    // ---- persistent weight fragments (loaded once per block) ----
    s8 wcf[4], w1f[2][4], w2f[8];
    #pragma unroll
    for (int k0 = 0; k0 < 4; ++k0)
        wcf[k0] = *reinterpret_cast<const s8*>(WcT + (cw * 16 + c) * 128 + k0 * 32 + q * 8);
    #pragma unroll
    for (int nt = 0; nt < 2; ++nt)
        #pragma unroll
        for (int k0 = 0; k0 < 4; ++k0)
            w1f[nt][k0] = *reinterpret_cast<const s8*>(W1T + (cw * 32 + nt * 16 + c) * 128 + k0 * 32 + q * 8);
    #pragma unroll
    for (int k0 = 0; k0 < 8; ++k0)
        w2f[k0] = *reinterpret_cast<const s8*>(W2T + (cw * 16 + c) * 256 + k0 * 32 + q * 8);

    const float g1c  = g1[cw * 16 + c],  be1c = be1[cw * 16 + c];
    const float b1v0 = b1[cw * 32 + c],  b1v1 = b1[cw * 32 + 16 + c];
    const float b2c  = b2[cw * 16 + c];
    const float g2c  = g2[cw * 16 + c],  be2c = be2[cw * 16 + c];

    const int srow = t >> 4;    // staging row 0..63
    const int sti  = t & 15;    // staging 16B-chunk index

    // ---- prologue: prefetch tile0 P/Q into regs + stage ea tile0 -> buf0 ----
    float pr[2][4], qr[2][4];
    {
        const int e0 = blockIdx.x * ET;
        #pragma unroll
        for (int mt = 0; mt < 2; ++mt) {
            int4 e4r = *reinterpret_cast<const int4*>(&ei[e0 + mg * 32 + mt * 16 + q * 4]);
            int4 e4c = *reinterpret_cast<const int4*>(&ei[NE + e0 + mg * 32 + mt * 16 + q * 4]);
            int er[4] = {e4r.x, e4r.y, e4r.z, e4r.w};
            int ec[4] = {e4c.x, e4c.y, e4c.z, e4c.w};
            #pragma unroll
            for (int reg = 0; reg < 4; ++reg) {
                pr[mt][reg] = P[(size_t)er[reg] * 128 + cw * 16 + c];
                qr[mt][reg] = Q[(size_t)ec[reg] * 128 + cw * 16 + c];
            }
        }
        const float4* src = reinterpret_cast<const float4*>(
            edge_attr + (size_t)(e0 + srow) * 128 + sti * 8);
        float4 v0 = src[0], v1 = src[1];
        s8 bb;
        bb[0] = (short)f2bf(v0.x); bb[1] = (short)f2bf(v0.y);
        bb[2] = (short)f2bf(v0.z); bb[3] = (short)f2bf(v0.w);
        bb[4] = (short)f2bf(v1.x); bb[5] = (short)f2bf(v1.y);
        bb[6] = (short)f2bf(v1.z); bb[7] = (short)f2bf(v1.w);
        *reinterpret_cast<s8*>(&lds_a[srow * PA + sti * 8]) = bb;
    }
    int cur = 0;

    for (int tile = blockIdx.x; tile < NTILE; tile += FFN_GRID) {
        const int e0 = tile * ET;
        __syncthreads();                                   // (A) ea[t] ready, P/Q[t] in regs

        short* bufC = lds_a + cur * (ET * PA);
        short* bufN = lds_a + (cur ^ 1) * (ET * PA);

        const int tn  = tile + FFN_GRID;
        const int e0n = (tn < NTILE ? tn : tile) * ET;     // clamp; values unused on last iter

        // ---- prefetch next-tile ei (int4) — arrives during GEMM1 ----
        int4 e4r[2], e4c[2];
        #pragma unroll
        for (int mt = 0; mt < 2; ++mt) {
            e4r[mt] = *reinterpret_cast<const int4*>(&ei[e0n + mg * 32 + mt * 16 + q * 4]);
            e4c[mt] = *reinterpret_cast<const int4*>(&ei[NE + e0n + mg * 32 + mt * 16 + q * 4]);
        }

        // ---- GEMM1: ea @ (Wc+I) from bufC ----
        f4 acc1[2];
        acc1[0] = {0.f, 0.f, 0.f, 0.f};
        acc1[1] = {0.f, 0.f, 0.f, 0.f};
        #pragma unroll
        for (int k0 = 0; k0 < 4; ++k0)
            #pragma unroll
            for (int mt = 0; mt < 2; ++mt) {
                s8 a = *reinterpret_cast<const s8*>(
                    &bufC[(mg * 32 + mt * 16 + c) * PA + k0 * 32 + q * 8]);
                acc1[mt] = __builtin_amdgcn_mfma_f32_16x16x32_bf16(a, wcf[k0], acc1[mt], 0, 0, 0);
            }

        // ---- consume prefetched P/Q (zero stall), then issue next-tile P/Q ----
        #pragma unroll
        for (int mt = 0; mt < 2; ++mt)
            #pragma unroll
            for (int reg = 0; reg < 4; ++reg)
                acc1[mt][reg] += pr[mt][reg] + qr[mt][reg];
        #pragma unroll
        for (int mt = 0; mt < 2; ++mt) {
            int er[4] = {e4r[mt].x, e4r[mt].y, e4r[mt].z, e4r[mt].w};
            int ec[4] = {e4c[mt].x, e4c[mt].y, e4c[mt].z, e4c[mt].w};
            #pragma unroll
            for (int reg = 0; reg < 4; ++reg) {
                pr[mt][reg] = P[(size_t)er[reg] * 128 + cw * 16 + c];
                qr[mt][reg] = Q[(size_t)ec[reg] * 128 + cw * 16 + c];
            }
        }

        // ---- issue next-tile ea loads (consumed pre-(D)) ----
        float4 nv0, nv1;
        {
            const float4* src = reinterpret_cast<const float4*>(
                edge_attr + (size_t)(e0n + srow) * 128 + sti * 8);
            nv0 = src[0]; nv1 = src[1];
        }

        // ---- LN1 partials -> red_part[mg][cw][r] ----
        #pragma unroll
        for (int mt = 0; mt < 2; ++mt)
            #pragma unroll
            for (int reg = 0; reg < 4; ++reg) {
                float v  = acc1[mt][reg];
                float sv = red16(v);
                float sq = red16(v * v);
                if (c == 0) {
                    int r = mt * 16 + q * 4 + reg;
                    float2 p2; p2.x = sv; p2.y = sq;
                    *reinterpret_cast<float2*>(&red_part[mg][cw][r][0]) = p2;
                }
            }
        __syncthreads();                                   // (B) partials ready

        // ---- LN1 stats: per-mg redundant reduce + shfl broadcast ----
        float mu_l = 0.f, rs_l = 0.f;
        if (lane < 32) {
            float s = 0.f, ss = 0.f;
            #pragma unroll
            for (int i = 0; i < 8; ++i) {
                float2 p2 = *reinterpret_cast<const float2*>(&red_part[mg][i][lane][0]);
                s += p2.x; ss += p2.y;
            }
            mu_l = s * (1.f / 128.f);
            float var = ss * (1.f / 128.f) - mu_l * mu_l;
            rs_l = rsqrtf(var + LN_EPS);
        }

        // ---- normalize -> h (bf16) into bufC ----
        #pragma unroll
        for (int mt = 0; mt < 2; ++mt)
            #pragma unroll
            for (int reg = 0; reg < 4; ++reg) {
                int r  = mt * 16 + q * 4 + reg;
                int gr = mg * 32 + r;
                float mu = __shfl(mu_l, r, 64);
                float rs = __shfl(rs_l, r, 64);
                float h = (acc1[mt][reg] - mu) * rs * g1c + be1c;
                bufC[gr * PA + cw * 16 + c] = (short)f2bf(h);
            }

        // ---- write next-tile ea into bufN (loads issued pre-LN1 — covered) ----
        {
            s8 bb;
            bb[0] = (short)f2bf(nv0.x); bb[1] = (short)f2bf(nv0.y);
            bb[2] = (short)f2bf(nv0.z); bb[3] = (short)f2bf(nv0.w);
            bb[4] = (short)f2bf(nv1.x); bb[5] = (short)f2bf(nv1.y);
            bb[6] = (short)f2bf(nv1.z); bb[7] = (short)f2bf(nv1.w);
            *reinterpret_cast<s8*>(&bufN[srow * PA + sti * 8]) = bb;
        }
        __syncthreads();                                   // (D) h ready

        // ---- GEMM2: u = relu(h @ W1 + b1) ----
        f4 acc2[2][2];
        acc2[0][0] = {0.f,0.f,0.f,0.f}; acc2[0][1] = {0.f,0.f,0.f,0.f};
        acc2[1][0] = {0.f,0.f,0.f,0.f}; acc2[1][1] = {0.f,0.f,0.f,0.f};
        #pragma unroll
        for (int k0 = 0; k0 < 4; ++k0)
            #pragma unroll
            for (int mt = 0; mt < 2; ++mt) {
                s8 a = *reinterpret_cast<const s8*>(
                    &bufC[(mg * 32 + mt * 16 + c) * PA + k0 * 32 + q * 8]);
                acc2[mt][0] = __builtin_amdgcn_mfma_f32_16x16x32_bf16(a, w1f[0][k0], acc2[mt][0], 0, 0, 0);
                acc2[mt][1] = __builtin_amdgcn_mfma_f32_16x16x32_bf16(a, w1f[1][k0], acc2[mt][1], 0, 0, 0);
            }
        #pragma unroll
        for (int mt = 0; mt < 2; ++mt)
            #pragma unroll
            for (int reg = 0; reg < 4; ++reg) {
                int gr = mg * 32 + mt * 16 + q * 4 + reg;
                float u0 = fmaxf(acc2[mt][0][reg] + b1v0, 0.f);
                float u1 = fmaxf(acc2[mt][1][reg] + b1v1, 0.f);
                lds_u[gr * PU + cw * 32 + c]      = (short)f2bf(u0);
                lds_u[gr * PU + cw * 32 + 16 + c] = (short)f2bf(u1);
            }
        __syncthreads();                                   // (E) u ready

        // ---- GEMM3: y = h + u @ W2 + b2 (K=256) ----
        f4 acc3[2];
        #pragma unroll
        for (int mt = 0; mt < 2; ++mt)
            #pragma unroll
            for (int reg = 0; reg < 4; ++reg) {
                int gr = mg * 32 + mt * 16 + q * 4 + reg;
                acc3[mt][reg] = bf2f((unsigned short)bufC[gr * PA + cw * 16 + c]) + b2c;
            }
        #pragma unroll
        for (int k0 = 0; k0 < 8; ++k0)
            #pragma unroll
            for (int mt = 0; mt < 2; ++mt) {
                s8 a = *reinterpret_cast<const s8*>(
                    &lds_u[(mg * 32 + mt * 16 + c) * PU + k0 * 32 + q * 8]);
                acc3[mt] = __builtin_amdgcn_mfma_f32_16x16x32_bf16(a, w2f[k0], acc3[mt], 0, 0, 0);
            }

        // ---- LN2 partials ----
        #pragma unroll
        for (int mt = 0; mt < 2; ++mt)
            #pragma unroll
            for (int reg = 0; reg < 4; ++reg) {
                float v  = acc3[mt][reg];
                float sv = red16(v);
                float sq = red16(v * v);
                if (c == 0) {
                    int r = mt * 16 + q * 4 + reg;
                    float2 p2; p2.x = sv; p2.y = sq;
                    *reinterpret_cast<float2*>(&red_part[mg][cw][r][0]) = p2;
                }
            }
        __syncthreads();                                   // (F) partials ready

        float mu2_l = 0.f, rs2_l = 0.f;
        if (lane < 32) {
            float s = 0.f, ss = 0.f;
            #pragma unroll
            for (int i = 0; i < 8; ++i) {
                float2 p2 = *reinterpret_cast<const float2*>(&red_part[mg][i][lane][0]);
                s += p2.x; ss += p2.y;
            }
            mu2_l = s * (1.f / 128.f);
            float var = ss * (1.f / 128.f) - mu2_l * mu2_l;
            rs2_l = rsqrtf(var + LN_EPS);
        }

        // ---- epilogue store ----
        #pragma unroll
        for (int mt = 0; mt < 2; ++mt)
            #pragma unroll
            for (int reg = 0; reg < 4; ++reg) {
                int r  = mt * 16 + q * 4 + reg;
                int gr = mg * 32 + r;
                float mu = __shfl(mu2_l, r, 64);
                float rs = __shfl(rs2_l, r, 64);
                float o = (acc3[mt][reg] - mu) * rs * g2c + be2c;
                out[(size_t)(e0 + gr) * 128 + cw * 16 + c] = o;
            }
        cur ^= 1;
    }
}

// ------------------------------------------------------------------ launch ---
extern "C" void kernel_launch(void* const* d_in, const int* in_sizes, int n_in,
                              void* d_out, int out_size, void* d_ws, size_t ws_size,
                              hipStream_t stream) {
    const float* x         = (const float*)d_in[0];
    const int*   ei        = (const int*)  d_in[1];
    const float* edge_attr = (const float*)d_in[2];
    const float* mask      = (const float*)d_in[3];
    const float* W_edge    = (const float*)d_in[5];
    const float* b_edge    = (const float*)d_in[6];
    const float* W1        = (const float*)d_in[7];
    const float* b1        = (const float*)d_in[8];
    const float* W2        = (const float*)d_in[9];
    const float* b2        = (const float*)d_in[10];
    const float* g1        = (const float*)d_in[11];
    const float* be1       = (const float*)d_in[12];
    const float* g2        = (const float*)d_in[13];
    const float* be2       = (const float*)d_in[14];

    float* node_out  = (float*)d_out;                       // [NN, DR]
    float* out_edges = (float*)d_out + (size_t)NN * DR;     // [NE, 128]

    char* ws = (char*)d_ws;
    int*            deg    = (int*)(ws);                         // 256 KB region
    int*            offs   = (int*)(ws + (256 << 10));           // 256 KB (NN+1 ints)
    int*            cursor = (int*)(ws + (512 << 10));           // 256 KB
    unsigned short* WcT    = (unsigned short*)(ws + (768 << 10));          // 32 KB
    unsigned short* W1T    = (unsigned short*)(ws + (768 << 10) + 32768);  // 64 KB
    unsigned short* W2T    = (unsigned short*)(ws + (768 << 10) + 98304);  // 64 KB
    int*            bucket = (int*)(ws + (1 << 20));             // 1.6 MB, aliases P (dead until pq)
    float*          P      = (float*)(ws + (1 << 20));           // 25.6 MB
    float*          Q      = (float*)(ws + (1 << 20) + 26214400);// 25.6 MB

    hipMemsetAsync(deg, 0, (size_t)NN * sizeof(int), stream);

    deg_kernel<<<(NE + 255) / 256, 256, 0, stream>>>(mask, ei, deg);
    scan_kernel<<<1, 1024, 0, stream>>>(deg, offs, cursor);
    binfill_kernel<<<(NE + 255) / 256, 256, 0, stream>>>(mask, ei, cursor, bucket);
    gather_kernel<<<(NN + 3) / 4, 256, 0, stream>>>(edge_attr, x, offs, bucket, node_out);
    prep_w_kernel<<<320, 256, 0, stream>>>(W_edge, W1, W2, WcT, W1T, W2T);
    pq_kernel<<<(NN + 63) / 64, 256, 0, stream>>>(node_out, W_edge, b_edge, P, Q);
    ffn_kernel<<<FFN_GRID, 1024, 0, stream>>>(edge_attr, ei, P, Q, WcT, W1T, W2T,
                                              b1, b2, g1, be1, g2, be2, out_edges);
}

// Round 6
// 848.021 us; speedup vs baseline: 1.3421x; 1.2721x over previous
//
#include <hip/hip_runtime.h>

// PathCon FFN — round 7: r2-exact ffn structure + f16 P/Q (halve gather bytes).
// Post-mortem r3-r5: every scheduling change (2 blocks/CU, lgkm-only barriers,
// next-tile prefetch) blew up L2 fill (450 MB -> 1.0-1.15 GB) by enlarging the
// live window of gathered P/Q lines. r2's issue-and-consume-in-one-phase is
// kept verbatim; bytes are reduced instead: P/Q stored as _Float16 (f16 ULP at
// |P|<=5 is ~0.004 — negligible vs existing 0.03125 bf16-residual error).
// gather: 2 rows/iter (float4 lanes + cross-half shfl combine).

#include <hip/hip_fp16.h>

constexpr int NN = 50000;
constexpr int NE = 400000;
constexpr int DI = 128;
constexpr int DN = 6;
constexpr int DR = 134;
constexpr float LN_EPS = 1e-5f;

using f4 = __attribute__((ext_vector_type(4))) float;
using s8 = __attribute__((ext_vector_type(8))) short;
using h4 = __attribute__((ext_vector_type(4))) _Float16;

__device__ __forceinline__ unsigned short f2bf(float f) {
    unsigned u = __float_as_uint(f);
    u += 0x7fff + ((u >> 16) & 1);   // RNE
    return (unsigned short)(u >> 16);
}

__device__ __forceinline__ float bf2f(unsigned short b) {
    return __uint_as_float((unsigned)b << 16);
}

// Sum across each aligned 16-lane group via DPP row rotations.
__device__ __forceinline__ float red16(float v) {
    int x;
    x = __builtin_amdgcn_update_dpp(0, __float_as_int(v), 0x121, 0xf, 0xf, true); // row_ror:1
    v += __int_as_float(x);
    x = __builtin_amdgcn_update_dpp(0, __float_as_int(v), 0x122, 0xf, 0xf, true); // row_ror:2
    v += __int_as_float(x);
    x = __builtin_amdgcn_update_dpp(0, __float_as_int(v), 0x124, 0xf, 0xf, true); // row_ror:4
    v += __int_as_float(x);
    x = __builtin_amdgcn_update_dpp(0, __float_as_int(v), 0x128, 0xf, 0xf, true); // row_ror:8
    v += __int_as_float(x);
    return v;
}

// ------------------------------------------------------------ CSR build ---
__global__ __launch_bounds__(256) void deg_kernel(
    const float* __restrict__ mask, const int* __restrict__ ei,
    int* __restrict__ deg)
{
    int e = blockIdx.x * 256 + threadIdx.x;
    if (e >= NE) return;
    if (mask[e] != 0.f) atomicAdd(&deg[ei[NE + e]], 1);
}

__global__ __launch_bounds__(1024) void scan_kernel(
    const int* __restrict__ deg, int* __restrict__ offs, int* __restrict__ cursor)
{
    __shared__ int part[1024];
    const int t = threadIdx.x;
    constexpr int CH = (NN + 1023) / 1024;   // 49
    const int base = t * CH;
    const int lim  = min(base + CH, NN);

    int s = 0;
    for (int i = base; i < lim; ++i) s += deg[i];
    part[t] = s;
    __syncthreads();
    for (int off = 1; off < 1024; off <<= 1) {
        int add = (t >= off) ? part[t - off] : 0;
        __syncthreads();
        part[t] += add;
        __syncthreads();
    }
    int run = (t == 0) ? 0 : part[t - 1];
    for (int i = base; i < lim; ++i) {
        offs[i]   = run;
        cursor[i] = run;
        run += deg[i];
    }
    if (t == 1023) offs[NN] = part[1023];
}

__global__ __launch_bounds__(256) void binfill_kernel(
    const float* __restrict__ mask, const int* __restrict__ ei,
    int* __restrict__ cursor, int* __restrict__ bucket)
{
    int e = blockIdx.x * 256 + threadIdx.x;
    if (e >= NE) return;
    if (mask[e] != 0.f) {
        int pos = atomicAdd(&cursor[ei[NE + e]], 1);
        bucket[pos] = e;
    }
}

// one wave per node, 2 edge-rows per iteration: lanes 0-31 sum even slots,
// lanes 32-63 odd slots (float4 per lane = 512B row), combined via shfl_xor.
// mask is binary (0/1): masked sum = plain sum of bucketed edges, den = count.
__global__ __launch_bounds__(256) void gather_kernel(
    const float* __restrict__ edge_attr, const float* __restrict__ x,
    const int* __restrict__ offs, const int* __restrict__ bucket,
    float* __restrict__ node_out)
{
    int n = blockIdx.x * 4 + (threadIdx.x >> 6);
    if (n >= NN) return;
    const int lane = threadIdx.x & 63;
    const int half = lane >> 5;      // 0 or 1
    const int sl   = lane & 31;      // 16B chunk index within row
    const int beg = offs[n], end = offs[n + 1];

    float4 acc = make_float4(0.f, 0.f, 0.f, 0.f);
    for (int j = beg + half; j < end; j += 2) {
        int e = bucket[j];
        float4 v = reinterpret_cast<const float4*>(edge_attr)[(size_t)e * 32 + sl];
        acc.x += v.x; acc.y += v.y; acc.z += v.z; acc.w += v.w;
    }
    acc.x += __shfl_xor(acc.x, 32, 64);
    acc.y += __shfl_xor(acc.y, 32, 64);
    acc.z += __shfl_xor(acc.z, 32, 64);
    acc.w += __shfl_xor(acc.w, 32, 64);

    float inv = 1.f / (float)(end - beg + 1);
    if (half == 0) {
        float2 o0 = make_float2(acc.x * inv, acc.y * inv);
        float2 o1 = make_float2(acc.z * inv, acc.w * inv);
        *reinterpret_cast<float2*>(node_out + (size_t)n * DR + sl * 4)     = o0;
        *reinterpret_cast<float2*>(node_out + (size_t)n * DR + sl * 4 + 2) = o1;
    }
    if (lane < DN) node_out[(size_t)n * DR + DI + lane] = x[n * DN + lane];
}

// ----------------------------------------------------- bf16 weight prep ---
__global__ __launch_bounds__(256) void prep_w_kernel(
    const float* __restrict__ W_edge, const float* __restrict__ W1,
    const float* __restrict__ W2,
    unsigned short* __restrict__ WcT, unsigned short* __restrict__ W1T,
    unsigned short* __restrict__ W2T)
{
    int idx = blockIdx.x * 256 + threadIdx.x;
    if (idx < 16384) {
        int n = idx >> 7, k = idx & 127;
        float v = W_edge[(268 + k) * 128 + n] + (k == n ? 1.f : 0.f);
        WcT[n * 128 + k] = f2bf(v);
    } else if (idx < 49152) {
        int j = idx - 16384;
        int n = j >> 7, k = j & 127;
        W1T[n * 128 + k] = f2bf(W1[k * 256 + n]);
    } else if (idx < 81920) {
        int j = idx - 49152;
        int n = j >> 8, k = j & 255;
        W2T[n * 256 + k] = f2bf(W2[k * 128 + n]);
    }
}

// ------------------------------------------------ P/Q node-level GEMMs ---
// f32 math; stores f16 (halves ffn gather bytes; f16 ULP ~0.004 at |P|<=5).
__global__ __launch_bounds__(256) void pq_kernel(
    const float* __restrict__ nr, const float* __restrict__ W_edge,
    const float* __restrict__ b_edge,
    _Float16* __restrict__ P, _Float16* __restrict__ Q)
{
    __shared__ float As[64 * 136];
    const int t = threadIdx.x;
    const int n0 = blockIdx.x * 64;

    for (int idx = t; idx < 64 * 136; idx += 256) {
        int n = idx / 136, k = idx - n * 136;
        float v = 0.f;
        if (n0 + n < NN && k < DR) v = nr[(size_t)(n0 + n) * DR + k];
        As[idx] = v;
    }
    __syncthreads();

    const int et = t >> 5, jt = t & 31;
    float4 accP[8], accQ[8];
    #pragma unroll
    for (int i = 0; i < 8; ++i) {
        accP[i] = make_float4(0.f, 0.f, 0.f, 0.f);
        accQ[i] = make_float4(0.f, 0.f, 0.f, 0.f);
    }
    for (int k0 = 0; k0 < 136; k0 += 4) {
        float4 wa[4], wb[4];
        #pragma unroll
        for (int d = 0; d < 4; ++d) {
            wa[d] = *reinterpret_cast<const float4*>(&W_edge[(size_t)(k0 + d) * 128 + 4 * jt]);
            wb[d] = *reinterpret_cast<const float4*>(&W_edge[(size_t)(134 + k0 + d) * 128 + 4 * jt]);
        }
        #pragma unroll
        for (int i = 0; i < 8; ++i) {
            float4 a4 = *reinterpret_cast<const float4*>(&As[(8 * et + i) * 136 + k0]);
            accP[i].x += a4.x * wa[0].x + a4.y * wa[1].x + a4.z * wa[2].x + a4.w * wa[3].x;
            accP[i].y += a4.x * wa[0].y + a4.y * wa[1].y + a4.z * wa[2].y + a4.w * wa[3].y;
            accP[i].z += a4.x * wa[0].z + a4.y * wa[1].z + a4.z * wa[2].z + a4.w * wa[3].z;
            accP[i].w += a4.x * wa[0].w + a4.y * wa[1].w + a4.z * wa[2].w + a4.w * wa[3].w;
            accQ[i].x += a4.x * wb[0].x + a4.y * wb[1].x + a4.z * wb[2].x + a4.w * wb[3].x;
            accQ[i].y += a4.x * wb[0].y + a4.y * wb[1].y + a4.z * wb[2].y + a4.w * wb[3].y;
            accQ[i].z += a4.x * wb[0].z + a4.y * wb[1].z + a4.z * wb[2].z + a4.w * wb[3].z;
            accQ[i].w += a4.x * wb[0].w + a4.y * wb[1].w + a4.z * wb[2].w + a4.w * wb[3].w;
        }
    }
    float4 bev = *reinterpret_cast<const float4*>(&b_edge[4 * jt]);
    #pragma unroll
    for (int i = 0; i < 8; ++i) {
        int n = n0 + 8 * et + i;
        if (n < NN) {
            h4 hp, hq;
            hp[0] = (_Float16)(accP[i].x + bev.x);
            hp[1] = (_Float16)(accP[i].y + bev.y);
            hp[2] = (_Float16)(accP[i].z + bev.z);
            hp[3] = (_Float16)(accP[i].w + bev.w);
            hq[0] = (_Float16)accQ[i].x;
            hq[1] = (_Float16)accQ[i].y;
            hq[2] = (_Float16)accQ[i].z;
            hq[3] = (_Float16)accQ[i].w;
            *reinterpret_cast<h4*>(&P[(size_t)n * 128 + 4 * jt]) = hp;
            *reinterpret_cast<h4*>(&Q[(size_t)n * 128 + 4 * jt]) = hq;
        }
    }
}

// -------------------------------------------------------------- fused FFN ---
// EXACT round-2 structure (310 us known-good): 1024 thr = 16 waves =
// 2 m-groups x 8 col-waves, ET=64, grid 256, plain __syncthreads (7/tile),
// PA=136/PU=264 pitches, weights in VGPRs. Only change: P/Q are _Float16.
constexpr int PA = 136;
constexpr int PU = 264;
constexpr int ET = 64;
constexpr int NTILE = NE / ET;   // 6250
constexpr int FFN_GRID = 256;

__global__ __launch_bounds__(1024, 4) void ffn_kernel(
    const float* __restrict__ edge_attr,  // [NE, 128]
    const int* __restrict__ ei,           // [2, NE]
    const _Float16* __restrict__ P,       // [NN, 128] f16
    const _Float16* __restrict__ Q,       // [NN, 128] f16
    const unsigned short* __restrict__ WcT,   // [128][128] bf16 (Wc+I)^T
    const unsigned short* __restrict__ W1T,   // [256][128] bf16
    const unsigned short* __restrict__ W2T,   // [128][256] bf16
    const float* __restrict__ b1, const float* __restrict__ b2,
    const float* __restrict__ g1, const float* __restrict__ be1,
    const float* __restrict__ g2, const float* __restrict__ be2,
    float* __restrict__ out)              // [NE, 128]
{
    __shared__ short lds_a[ET * PA];          // ea tile, later h tile (17408 B)
    __shared__ short lds_u[ET * PU];          // u tile (33792 B)
    __shared__ float red_part[2][8][32][2];   // [mg][cw][row][s,ss] (4096 B)
    __shared__ float musig[2][ET][2];         // [ln][row][mu,rs]    (1024 B)

    const int t    = threadIdx.x;
    const int w    = t >> 6;
    const int lane = t & 63;
    const int q    = lane >> 4;     // 0..3
    const int c    = lane & 15;     // 0..15
    const int mg   = w >> 3;        // 0..1
    const int cw   = w & 7;         // 0..7

    // ---- persistent weight fragments (loaded once per block) ----
    s8 wcf[4], w1f[2][4], w2f[8];
    #pragma unroll
    for (int k0 = 0; k0 < 4; ++k0)
        wcf[k0] = *reinterpret_cast<const s8*>(WcT + (cw * 16 + c) * 128 + k0 * 32 + q * 8);
    #pragma unroll
    for (int nt = 0; nt < 2; ++nt)
        #pragma unroll
        for (int k0 = 0; k0 < 4; ++k0)
            w1f[nt][k0] = *reinterpret_cast<const s8*>(W1T + (cw * 32 + nt * 16 + c) * 128 + k0 * 32 + q * 8);
    #pragma unroll
    for (int k0 = 0; k0 < 8; ++k0)
        w2f[k0] = *reinterpret_cast<const s8*>(W2T + (cw * 16 + c) * 256 + k0 * 32 + q * 8);

    const float g1c  = g1[cw * 16 + c],  be1c = be1[cw * 16 + c];
    const float b1v0 = b1[cw * 32 + c],  b1v1 = b1[cw * 32 + 16 + c];
    const float b2c  = b2[cw * 16 + c];
    const float g2c  = g2[cw * 16 + c],  be2c = be2[cw * 16 + c];

    const int srow = t >> 4;    // staging: 0..63
    const int sti  = t & 15;    // staging: 16 threads per row

    for (int tile = blockIdx.x; tile < NTILE; tile += gridDim.x) {
        const int e0 = tile * ET;

        // ---- stage ea tile -> bf16 LDS (all 1024 threads, 8 floats each) ----
        {
            const float4* src = reinterpret_cast<const float4*>(
                edge_attr + (size_t)(e0 + srow) * 128 + sti * 8);
            float4 v0 = src[0], v1 = src[1];
            s8 bb;
            bb[0] = (short)f2bf(v0.x); bb[1] = (short)f2bf(v0.y);
            bb[2] = (short)f2bf(v0.z); bb[3] = (short)f2bf(v0.w);
            bb[4] = (short)f2bf(v1.x); bb[5] = (short)f2bf(v1.y);
            bb[6] = (short)f2bf(v1.z); bb[7] = (short)f2bf(v1.w);
            *reinterpret_cast<s8*>(&lds_a[srow * PA + sti * 8]) = bb;
        }
        __syncthreads();                                   // (A) ea ready

        // ---- GEMM1: ea @ (Wc+I) ----
        f4 acc1[2];
        acc1[0] = {0.f, 0.f, 0.f, 0.f};
        acc1[1] = {0.f, 0.f, 0.f, 0.f};
        #pragma unroll
        for (int k0 = 0; k0 < 4; ++k0)
            #pragma unroll
            for (int mt = 0; mt < 2; ++mt) {
                s8 a = *reinterpret_cast<const s8*>(&lds_a[(mg * 32 + mt * 16 + c) * PA + k0 * 32 + q * 8]);
                acc1[mt] = __builtin_amdgcn_mfma_f32_16x16x32_bf16(a, wcf[k0], acc1[mt], 0, 0, 0);
            }

        // ---- residual: + P[row_e] + Q[col_e] (f16 loads) ----
        #pragma unroll
        for (int mt = 0; mt < 2; ++mt)
            #pragma unroll
            for (int reg = 0; reg < 4; ++reg) {
                int e  = e0 + mg * 32 + mt * 16 + q * 4 + reg;
                int er = ei[e], ec = ei[NE + e];
                acc1[mt][reg] += (float)P[(size_t)er * 128 + cw * 16 + c]
                               + (float)Q[(size_t)ec * 128 + cw * 16 + c];
            }

        // ---- LN1 partials ----
        #pragma unroll
        for (int mt = 0; mt < 2; ++mt)
            #pragma unroll
            for (int reg = 0; reg < 4; ++reg) {
                float v  = acc1[mt][reg];
                float sv = red16(v);
                float sq = red16(v * v);
                if (c == 0) {
                    int r = mt * 16 + q * 4 + reg;
                    float2 p2; p2.x = sv; p2.y = sq;
                    *reinterpret_cast<float2*>(&red_part[mg][cw][r][0]) = p2;
                }
            }
        __syncthreads();                                   // (B) partials ready
        if (t < ET) {
            float s = 0.f, ss = 0.f;
            #pragma unroll
            for (int i = 0; i < 8; ++i) {
                float2 p2 = *reinterpret_cast<const float2*>(&red_part[t >> 5][i][t & 31][0]);
                s += p2.x; ss += p2.y;
            }
            float mu  = s * (1.f / 128.f);
            float var = ss * (1.f / 128.f) - mu * mu;
            float2 m2; m2.x = mu; m2.y = rsqrtf(var + LN_EPS);
            *reinterpret_cast<float2*>(&musig[0][t][0]) = m2;
        }
        __syncthreads();                                   // (C) mu/rs ready

        // ---- normalize -> h (bf16) into lds_a ----
        #pragma unroll
        for (int mt = 0; mt < 2; ++mt)
            #pragma unroll
            for (int reg = 0; reg < 4; ++reg) {
                int r = mg * 32 + mt * 16 + q * 4 + reg;
                float2 m2 = *reinterpret_cast<const float2*>(&musig[0][r][0]);
                float h = (acc1[mt][reg] - m2.x) * m2.y * g1c + be1c;
                lds_a[r * PA + cw * 16 + c] = (short)f2bf(h);
            }
        __syncthreads();                                   // (D) h ready

        // ---- GEMM2: u = relu(h @ W1 + b1) ----
        f4 acc2[2][2];
        acc2[0][0] = {0.f,0.f,0.f,0.f}; acc2[0][1] = {0.f,0.f,0.f,0.f};
        acc2[1][0] = {0.f,0.f,0.f,0.f}; acc2[1][1] = {0.f,0.f,0.f,0.f};
        #pragma unroll
        for (int k0 = 0; k0 < 4; ++k0)
            #pragma unroll
            for (int mt = 0; mt < 2; ++mt) {
                s8 a = *reinterpret_cast<const s8*>(&lds_a[(mg * 32 + mt * 16 + c) * PA + k0 * 32 + q * 8]);
                acc2[mt][0] = __builtin_amdgcn_mfma_f32_16x16x32_bf16(a, w1f[0][k0], acc2[mt][0], 0, 0, 0);
                acc2[mt][1] = __builtin_amdgcn_mfma_f32_16x16x32_bf16(a, w1f[1][k0], acc2[mt][1], 0, 0, 0);
            }
        #pragma unroll
        for (int mt = 0; mt < 2; ++mt)
            #pragma unroll
            for (int reg = 0; reg < 4; ++reg) {
                int r = mg * 32 + mt * 16 + q * 4 + reg;
                float u0 = fmaxf(acc2[mt][0][reg] + b1v0, 0.f);
                float u1 = fmaxf(acc2[mt][1][reg] + b1v1, 0.f);
                lds_u[r * PU + cw * 32 + c]      = (short)f2bf(u0);
                lds_u[r * PU + cw * 32 + 16 + c] = (short)f2bf(u1);
            }
        __syncthreads();                                   // (E) u ready

        // ---- GEMM3: y = h + u @ W2 + b2 (K=256) ----
        f4 acc3[2];
        #pragma unroll
        for (int mt = 0; mt < 2; ++mt)
            #pragma unroll
            for (int reg = 0; reg < 4; ++reg) {
                int r = mg * 32 + mt * 16 + q * 4 + reg;
                acc3[mt][reg] = bf2f((unsigned short)lds_a[r * PA + cw * 16 + c]) + b2c;
            }
        #pragma unroll
        for (int k0 = 0; k0 < 8; ++k0)
            #pragma unroll
            for (int mt = 0; mt < 2; ++mt) {
                s8 a = *reinterpret_cast<const s8*>(&lds_u[(mg * 32 + mt * 16 + c) * PU + k0 * 32 + q * 8]);
                acc3[mt] = __builtin_amdgcn_mfma_f32_16x16x32_bf16(a, w2f[k0], acc3[mt], 0, 0, 0);
            }

        // ---- LN2 partials ----
        #pragma unroll
        for (int mt = 0; mt < 2; ++mt)
            #pragma unroll
            for (int reg = 0; reg < 4; ++reg) {
                float v  = acc3[mt][reg];
                float sv = red16(v);
                float sq = red16(v * v);
                if (c == 0) {
                    int r = mt * 16 + q * 4 + reg;
                    float2 p2; p2.x = sv; p2.y = sq;
                    *reinterpret_cast<float2*>(&red_part[mg][cw][r][0]) = p2;
                }
            }
        __syncthreads();                                   // (F) partials ready
        if (t < ET) {
            float s = 0.f, ss = 0.f;
            #pragma unroll
            for (int i = 0; i < 8; ++i) {
                float2 p2 = *reinterpret_cast<const float2*>(&red_part[t >> 5][i][t & 31][0]);
                s += p2.x; ss += p2.y;
            }
            float mu  = s * (1.f / 128.f);
            float var = ss * (1.f / 128.f) - mu * mu;
            float2 m2; m2.x = mu; m2.y = rsqrtf(var + LN_EPS);
            *reinterpret_cast<float2*>(&musig[1][t][0]) = m2;
        }
        __syncthreads();                                   // (G) mu/rs ready

        // ---- epilogue store ----
        #pragma unroll
        for (int mt = 0; mt < 2; ++mt)
            #pragma unroll
            for (int reg = 0; reg < 4; ++reg) {
                int r = mg * 32 + mt * 16 + q * 4 + reg;
                float2 m2 = *reinterpret_cast<const float2*>(&musig[1][r][0]);
                float o = (acc3[mt][reg] - m2.x) * m2.y * g2c + be2c;
                out[(size_t)(e0 + r) * 128 + cw * 16 + c] = o;
            }
    }
}

// ------------------------------------------------------------------ launch ---
extern "C" void kernel_launch(void* const* d_in, const int* in_sizes, int n_in,
                              void* d_out, int out_size, void* d_ws, size_t ws_size,
                              hipStream_t stream) {
    const float* x         = (const float*)d_in[0];
    const int*   ei        = (const int*)  d_in[1];
    const float* edge_attr = (const float*)d_in[2];
    const float* mask      = (const float*)d_in[3];
    const float* W_edge    = (const float*)d_in[5];
    const float* b_edge    = (const float*)d_in[6];
    const float* W1        = (const float*)d_in[7];
    const float* b1        = (const float*)d_in[8];
    const float* W2        = (const float*)d_in[9];
    const float* b2        = (const float*)d_in[10];
    const float* g1        = (const float*)d_in[11];
    const float* be1       = (const float*)d_in[12];
    const float* g2        = (const float*)d_in[13];
    const float* be2       = (const float*)d_in[14];

    float* node_out  = (float*)d_out;                       // [NN, DR]
    float* out_edges = (float*)d_out + (size_t)NN * DR;     // [NE, 128]

    char* ws = (char*)d_ws;
    int*            deg    = (int*)(ws);                         // 256 KB region
    int*            offs   = (int*)(ws + (256 << 10));           // 256 KB (NN+1 ints)
    int*            cursor = (int*)(ws + (512 << 10));           // 256 KB
    unsigned short* WcT    = (unsigned short*)(ws + (768 << 10));          // 32 KB
    unsigned short* W1T    = (unsigned short*)(ws + (768 << 10) + 32768);  // 64 KB
    unsigned short* W2T    = (unsigned short*)(ws + (768 << 10) + 98304);  // 64 KB
    int*            bucket = (int*)(ws + (1 << 20));             // 1.6 MB, aliases P (dead until pq)
    _Float16*       P      = (_Float16*)(ws + (1 << 20));        // 12.8 MB (f16)
    _Float16*       Q      = (_Float16*)(ws + (1 << 20) + 13631488); // 12.8 MB (f16)

    hipMemsetAsync(deg, 0, (size_t)NN * sizeof(int), stream);

    deg_kernel<<<(NE + 255) / 256, 256, 0, stream>>>(mask, ei, deg);
    scan_kernel<<<1, 1024, 0, stream>>>(deg, offs, cursor);
    binfill_kernel<<<(NE + 255) / 256, 256, 0, stream>>>(mask, ei, cursor, bucket);
    gather_kernel<<<(NN + 3) / 4, 256, 0, stream>>>(edge_attr, x, offs, bucket, node_out);
    prep_w_kernel<<<320, 256, 0, stream>>>(W_edge, W1, W2, WcT, W1T, W2T);
    pq_kernel<<<(NN + 63) / 64, 256, 0, stream>>>(node_out, W_edge, b_edge, P, Q);
    ffn_kernel<<<FFN_GRID, 1024, 0, stream>>>(edge_attr, ei, P, Q, WcT, W1T, W2T,
                                              b1, b2, g1, be1, g2, be2, out_edges);
}